// Round 4
// baseline (5757.722 us; speedup 1.0000x reference)
//
#include <hip/hip_runtime.h>
#include <hip/hip_bf16.h>

typedef __bf16 bf16;
typedef __bf16 bf16x8 __attribute__((ext_vector_type(8)));
typedef float f32x4 __attribute__((ext_vector_type(4)));

#define MODE_BIAS 1
#define MODE_RELU 2
#define MODE_BF16 4
#define MODE_F32  8
#define MODE_RES  16
#define MODE_MASK 32
#define MODE_VT   64
#define MODE_QKV  128

// ---------------------------------------------------------------------------
// Async 16B global->LDS stage (wave-uniform LDS base + lane*16 hardware dest)
// ---------------------------------------------------------------------------
__device__ __forceinline__ void stage16(const bf16* g, bf16* l)
{
  __builtin_amdgcn_global_load_lds(
      (const __attribute__((address_space(1))) void*)g,
      (__attribute__((address_space(3))) void*)l, 16, 0, 0);
}

// ---------------------------------------------------------------------------
// FAST aligned bf16 MFMA GEMM (m97 structure): C[M,N]=A[M,K]*B^T, M%128==0,
// N%128==0, K%32==0. 128x128 tile, BK=32, global_load_lds width-16 staging.
// QKV mode: N=12288 merged; V part (bn0>=8192) stored transposed via LDS
// transpose tile for coalesced writes.
// ---------------------------------------------------------------------------
__global__ __launch_bounds__(256) void gemm_fast(
    const bf16* __restrict__ A, const bf16* __restrict__ B,
    float* __restrict__ Cf, bf16* __restrict__ Cb,
    const float* __restrict__ bias, const float* __restrict__ res,
    int N, int K, int lda, int ldb, int ldc, long qstride, int mode)
{
  __shared__ __attribute__((aligned(16))) bf16 sA[128 * 32];
  __shared__ __attribute__((aligned(16))) bf16 sB[128 * 32];
  __shared__ __attribute__((aligned(16))) bf16 sS[64 * 130];  // V-transpose tile

  int tid  = threadIdx.x;
  int lane = tid & 63;
  int wave = tid >> 6;
  int wm = (wave >> 1) * 64;
  int wn = (wave & 1) * 64;
  int bm0 = blockIdx.y * 128;
  int bn0 = blockIdx.x * 128;

  f32x4 acc[4][4];
  #pragma unroll
  for (int i = 0; i < 4; ++i)
    #pragma unroll
    for (int j = 0; j < 4; ++j)
      #pragma unroll
      for (int r = 0; r < 4; ++r) acc[i][j][r] = 0.f;

  int seg0 = wave;
  int o0 = seg0 * 1024 + lane * 16;
  int row0s = o0 >> 6, colb0 = o0 & 63;
  int seg1 = wave + 4;
  int o1 = seg1 * 1024 + lane * 16;
  int row1s = o1 >> 6, colb1 = o1 & 63;

  const char* gA0 = (const char*)A + ((long)(bm0 + row0s) * lda) * 2 + colb0;
  const char* gA1 = (const char*)A + ((long)(bm0 + row1s) * lda) * 2 + colb1;
  const char* gB0 = (const char*)B + ((long)(bn0 + row0s) * ldb) * 2 + colb0;
  const char* gB1 = (const char*)B + ((long)(bn0 + row1s) * ldb) * 2 + colb1;

  for (int k0 = 0; k0 < K; k0 += 32) {
    stage16((const bf16*)(gA0 + (long)k0 * 2), &sA[seg0 * 512]);
    stage16((const bf16*)(gA1 + (long)k0 * 2), &sA[seg1 * 512]);
    stage16((const bf16*)(gB0 + (long)k0 * 2), &sB[seg0 * 512]);
    stage16((const bf16*)(gB1 + (long)k0 * 2), &sB[seg1 * 512]);
    __syncthreads();
    bf16x8 aF[4], bF[4];
    #pragma unroll
    for (int i = 0; i < 4; ++i)
      aF[i] = *(const bf16x8*)(&sA[(wm + i * 16 + (lane & 15)) * 32 + (lane >> 4) * 8]);
    #pragma unroll
    for (int j = 0; j < 4; ++j)
      bF[j] = *(const bf16x8*)(&sB[(wn + j * 16 + (lane & 15)) * 32 + (lane >> 4) * 8]);
    #pragma unroll
    for (int i = 0; i < 4; ++i)
      #pragma unroll
      for (int j = 0; j < 4; ++j)
        acc[i][j] = __builtin_amdgcn_mfma_f32_16x16x32_bf16(aF[i], bF[j], acc[i][j], 0, 0, 0);
    __syncthreads();
  }

  int lg = lane >> 4;
  int r0 = lg * 4;
  int cc = lane & 15;

  if ((mode & MODE_QKV) && bn0 >= 8192) {
    // ---- V: transposed coalesced store via LDS ----
    int nn0 = bn0 - 8192;
    #pragma unroll
    for (int ph = 0; ph < 2; ++ph) {
      if ((wn >> 6) == ph) {
        #pragma unroll
        for (int j = 0; j < 4; ++j) {
          int nl = j * 16 + cc;                    // 0..63 within half
          float bv = bias[bn0 + wn + j * 16 + cc];
          #pragma unroll
          for (int i = 0; i < 4; ++i)
            #pragma unroll
            for (int r = 0; r < 4; ++r) {
              int m = wm + i * 16 + r0 + r;        // 0..127
              sS[nl * 130 + m] = (bf16)(acc[i][j][r] + bv);
            }
        }
      }
      __syncthreads();
      #pragma unroll
      for (int u = 0; u < 16; ++u) {
        int nrow = u * 4 + wave;                   // 0..63
        int d = nn0 + ph * 64 + nrow;              // 0..4095
        int hh = d >> 9, dd = d & 511;
        unsigned int pv = *(const unsigned int*)&sS[nrow * 130 + lane * 2];
        int m0 = bm0 + 2 * lane;
        int bl = m0 / 168;
        int s  = m0 - bl * 168;                    // even, so pair never crosses bl
        *(unsigned int*)&Cb[2 * qstride + ((long)(bl * 8 + hh) * 512 + dd) * 168 + s] = pv;
      }
      __syncthreads();
    }
    return;
  }

  #pragma unroll
  for (int j = 0; j < 4; ++j) {
    int gn = bn0 + wn + j * 16 + cc;
    float bv = (mode & MODE_BIAS) ? bias[gn] : 0.f;
    #pragma unroll
    for (int i = 0; i < 4; ++i) {
      #pragma unroll
      for (int r = 0; r < 4; ++r) {
        int gm = bm0 + wm + i * 16 + r0 + r;
        float v = acc[i][j][r] + bv;
        if (mode & MODE_RES) v += res[(long)gm * ldc + gn];
        if (mode & MODE_RELU) v = fmaxf(v, 0.f);
        if (mode & MODE_QKV) {
          int part = gn >> 12;      // 0=Q 1=K here (V handled above)
          int n = gn & 4095;
          Cb[(long)part * qstride + (long)gm * 4096 + n] = (bf16)v;
        } else if (mode & MODE_F32) {
          Cf[(long)gm * ldc + gn] = v;
        } else if (mode & MODE_BF16) {
          Cb[(long)gm * ldc + gn] = (bf16)v;
        }
      }
    }
  }
}

// ---------------------------------------------------------------------------
// GEMM (N=512 full-width) + bias + residual + LayerNorm, fused.
// C[M,512] = A[M,K]*B^T + bias + res; Yf/Yb = LN(C)*g+b.  M%64==0, K%32==0.
// 512 threads = 8 waves as 2(m)x4(n); wave tile 32x128; C stays in registers;
// row mean/var via width-16 shfl + cross-wave LDS combine.
// ---------------------------------------------------------------------------
__global__ __launch_bounds__(512) void gemm_ln(
    const bf16* __restrict__ A, const bf16* __restrict__ B,
    const float* __restrict__ bias, const float* __restrict__ res,
    const float* __restrict__ gam, const float* __restrict__ bet,
    float* __restrict__ Yf, bf16* __restrict__ Yb, int K)
{
  __shared__ __attribute__((aligned(16))) bf16 sA[64 * 32];
  __shared__ __attribute__((aligned(16))) bf16 sB[512 * 32];
  __shared__ float redS[4][64];
  __shared__ float redQ[4][64];

  int tid = threadIdx.x, lane = tid & 63, wave = tid >> 6;
  int wm = (wave >> 2) * 32;
  int wn = (wave & 3) * 128;
  int bm0 = blockIdx.x * 64;

  f32x4 acc[2][8];
  #pragma unroll
  for (int i = 0; i < 2; ++i)
    #pragma unroll
    for (int j = 0; j < 8; ++j)
      #pragma unroll
      for (int r = 0; r < 4; ++r) acc[i][j][r] = 0.f;

  int rsub = lane >> 2;             // 0..15 row-within-seg
  int colb = (lane & 3) * 16;       // byte col 0..48
  const char* gB[4];
  #pragma unroll
  for (int u = 0; u < 4; ++u) {
    int row = (wave * 4 + u) * 16 + rsub;           // B row (= out col)
    gB[u] = (const char*)B + ((long)row * K) * 2 + colb;
  }
  const char* gA = (const char*)A;  // valid only for wave<4
  {
    int row = wave * 16 + rsub;
    if (wave < 4) gA = (const char*)A + ((long)(bm0 + row) * K) * 2 + colb;
  }

  for (int k0 = 0; k0 < K; k0 += 32) {
    #pragma unroll
    for (int u = 0; u < 4; ++u)
      stage16((const bf16*)(gB[u] + (long)k0 * 2), &sB[(wave * 4 + u) * 512]);
    if (wave < 4)
      stage16((const bf16*)(gA + (long)k0 * 2), &sA[wave * 512]);
    __syncthreads();
    bf16x8 aF[2], bF[8];
    #pragma unroll
    for (int i = 0; i < 2; ++i)
      aF[i] = *(const bf16x8*)(&sA[(wm + i * 16 + (lane & 15)) * 32 + (lane >> 4) * 8]);
    #pragma unroll
    for (int j = 0; j < 8; ++j)
      bF[j] = *(const bf16x8*)(&sB[(wn + j * 16 + (lane & 15)) * 32 + (lane >> 4) * 8]);
    #pragma unroll
    for (int i = 0; i < 2; ++i)
      #pragma unroll
      for (int j = 0; j < 8; ++j)
        acc[i][j] = __builtin_amdgcn_mfma_f32_16x16x32_bf16(aF[i], bF[j], acc[i][j], 0, 0, 0);
    __syncthreads();
  }

  int lg = lane >> 4, cc = lane & 15;
  float bv[8], gv[8], btv[8];
  #pragma unroll
  for (int j = 0; j < 8; ++j) {
    int n = wn + j * 16 + cc;
    bv[j] = bias[n]; gv[j] = gam[n]; btv[j] = bet[n];
  }

  #pragma unroll
  for (int i = 0; i < 2; ++i) {
    #pragma unroll
    for (int r = 0; r < 4; ++r) {
      int row = wm + i * 16 + lg * 4 + r;           // 0..63
      long grow = bm0 + row;
      float s = 0.f, q = 0.f;
      #pragma unroll
      for (int j = 0; j < 8; ++j) {
        float v = acc[i][j][r] + bv[j] + res[grow * 512 + wn + j * 16 + cc];
        acc[i][j][r] = v;
        s += v; q += v * v;
      }
      #pragma unroll
      for (int off = 1; off < 16; off <<= 1) {
        s += __shfl_xor(s, off, 16);
        q += __shfl_xor(q, off, 16);
      }
      if (cc == 0) { redS[wave & 3][row] = s; redQ[wave & 3][row] = q; }
    }
  }
  __syncthreads();
  #pragma unroll
  for (int i = 0; i < 2; ++i) {
    #pragma unroll
    for (int r = 0; r < 4; ++r) {
      int row = wm + i * 16 + lg * 4 + r;
      long grow = bm0 + row;
      float tot = redS[0][row] + redS[1][row] + redS[2][row] + redS[3][row];
      float tq  = redQ[0][row] + redQ[1][row] + redQ[2][row] + redQ[3][row];
      float mean = tot * (1.f / 512.f);
      float var  = tq * (1.f / 512.f) - mean * mean;
      float rs = rsqrtf(var + 1e-9f);
      #pragma unroll
      for (int j = 0; j < 8; ++j) {
        int n = wn + j * 16 + cc;
        float y = (acc[i][j][r] - mean) * rs * gv[j] + btv[j];
        Yf[grow * 512 + n] = y;
        Yb[grow * 512 + n] = (bf16)y;
      }
    }
  }
}

// ---------------------------------------------------------------------------
// FUSED ATTENTION (unchanged from R3)
// ---------------------------------------------------------------------------
__global__ __launch_bounds__(256) void attn_fused(
    const bf16* __restrict__ Q, const bf16* __restrict__ K,
    const bf16* __restrict__ Vt, bf16* __restrict__ O)
{
  __shared__ __attribute__((aligned(16))) bf16 sQ[64 * 32];
  __shared__ __attribute__((aligned(16))) bf16 sK[192 * 32];
  __shared__ __attribute__((aligned(16))) bf16 sP[64 * 200];
  __shared__ __attribute__((aligned(16))) bf16 sV[256 * 32];

  int mt = blockIdx.x;
  int bh = blockIdx.y;
  int bl = bh >> 3, h = bh & 7;
  int tid = threadIdx.x, lane = tid & 63, wave = tid >> 6;

  const bf16* Qb = Q + ((long)bl * 168 + mt * 64) * 4096 + h * 512;
  const bf16* Kb = K + (long)bl * 168 * 4096 + h * 512;
  const bf16* Vb = Vt + (long)bh * 512 * 168;

  #pragma unroll
  for (int idx = tid; idx < 64 * 16; idx += 256) {
    int rr = idx >> 4;
    sP[rr * 200 + 176 + (idx & 15)] = (bf16)0.f;
  }

  int o = wave * 1024 + lane * 16;
  int srw = o >> 6, scb = o & 63;

  const char* gQ = (const char*)Qb + (long)srw * 8192 + scb;
  const char* gK = (const char*)Kb + (long)srw * 8192 + scb;

  f32x4 sacc[11];
  #pragma unroll
  for (int j = 0; j < 11; ++j)
    #pragma unroll
    for (int r = 0; r < 4; ++r) sacc[j][r] = 0.f;

  for (int k0 = 0; k0 < 512; k0 += 32) {
    stage16((const bf16*)(gQ + (long)k0 * 2), &sQ[wave * 512]);
    stage16((const bf16*)(gK + (long)k0 * 2), &sK[wave * 512]);
    stage16((const bf16*)(gK + 64 * 8192 + (long)k0 * 2), &sK[(wave + 4) * 512]);
    stage16((const bf16*)(gK + 128 * 8192 + (long)k0 * 2), &sK[(wave + 8) * 512]);
    __syncthreads();
    bf16x8 aF = *(const bf16x8*)(&sQ[(wave * 16 + (lane & 15)) * 32 + (lane >> 4) * 8]);
    #pragma unroll
    for (int j = 0; j < 11; ++j) {
      bf16x8 bF = *(const bf16x8*)(&sK[(j * 16 + (lane & 15)) * 32 + (lane >> 4) * 8]);
      sacc[j] = __builtin_amdgcn_mfma_f32_16x16x32_bf16(aF, bF, sacc[j], 0, 0, 0);
    }
    __syncthreads();
  }

  int rbase = wave * 16 + ((lane >> 4) << 2);
  #pragma unroll
  for (int r = 0; r < 4; ++r) {
    int srow = mt * 64 + rbase + r;
    float mx = -1e30f;
    #pragma unroll
    for (int j = 0; j < 11; ++j) {
      int col = j * 16 + (lane & 15);
      float v = sacc[j][r] * 0.04419417382415922f;
      v = (col <= srow) ? v : -1e9f;
      sacc[j][r] = v;
      mx = fmaxf(mx, v);
    }
    #pragma unroll
    for (int off = 1; off < 16; off <<= 1) mx = fmaxf(mx, __shfl_xor(mx, off, 16));
    float sum = 0.f;
    #pragma unroll
    for (int j = 0; j < 11; ++j) {
      float e = __expf(sacc[j][r] - mx);
      sacc[j][r] = e;
      sum += e;
    }
    #pragma unroll
    for (int off = 1; off < 16; off <<= 1) sum += __shfl_xor(sum, off, 16);
    float inv = 1.f / sum;
    #pragma unroll
    for (int j = 0; j < 11; ++j)
      sP[(rbase + r) * 200 + j * 16 + (lane & 15)] = (bf16)(sacc[j][r] * inv);
  }

  const char* gV = (const char*)Vb + (long)srw * 336 + scb;
  #pragma unroll 1
  for (int nc = 0; nc < 2; ++nc) {
    f32x4 oacc[16];
    #pragma unroll
    for (int t = 0; t < 16; ++t)
      #pragma unroll
      for (int r = 0; r < 4; ++r) oacc[t][r] = 0.f;

    for (int k0 = 0; k0 < 192; k0 += 32) {
      #pragma unroll
      for (int u = 0; u < 4; ++u)
        stage16((const bf16*)(gV + (long)(nc * 256 + u * 64) * 336 + (long)k0 * 2),
                &sV[(wave + u * 4) * 512]);
      __syncthreads();
      bf16x8 aF = *(const bf16x8*)(&sP[(wave * 16 + (lane & 15)) * 200 + k0 + (lane >> 4) * 8]);
      #pragma unroll
      for (int t = 0; t < 16; ++t) {
        bf16x8 bF = *(const bf16x8*)(&sV[(t * 16 + (lane & 15)) * 32 + (lane >> 4) * 8]);
        oacc[t] = __builtin_amdgcn_mfma_f32_16x16x32_bf16(aF, bF, oacc[t], 0, 0, 0);
      }
      __syncthreads();
    }
    #pragma unroll
    for (int t = 0; t < 16; ++t) {
      int d = nc * 256 + t * 16 + (lane & 15);
      #pragma unroll
      for (int r = 0; r < 4; ++r) {
        int srow = mt * 64 + rbase + r;
        if (srow < 168)
          O[((long)bl * 168 + srow) * 4096 + h * 512 + d] = (bf16)oacc[t][r];
      }
    }
  }
}

// ---------------------------------------------------------------------------
// Generic bf16 MFMA GEMM (bounds-checked) — fallback for small workspace.
// ---------------------------------------------------------------------------
__device__ __forceinline__ bf16x8 load_g8(const bf16* __restrict__ p, long row,
                                          int ld, int gk, int rmax, int K)
{
  bf16x8 v;
  if (row < rmax) {
    const bf16* q = p + row * (long)ld + gk;
    if (gk + 8 <= K) {
      v = *(const bf16x8*)q;
    } else {
      #pragma unroll
      for (int e = 0; e < 8; ++e) v[e] = (gk + e < K) ? q[e] : (bf16)0.f;
    }
  } else {
    #pragma unroll
    for (int e = 0; e < 8; ++e) v[e] = (bf16)0.f;
  }
  return v;
}

__global__ __launch_bounds__(256) void gemm_bt(
    const bf16* __restrict__ A, const bf16* __restrict__ B,
    float* __restrict__ Cf, bf16* __restrict__ Cb,
    const float* __restrict__ bias, const float* __restrict__ res,
    int M, int N, int K, int lda, int ldb, int ldc,
    long sAb, long sAh, long sBb, long sBh, long sCb, long sCh,
    int mode, float scale)
{
  int z = blockIdx.z;
  A += (long)(z >> 3) * sAb + (long)(z & 7) * sAh;
  B += (long)(z >> 3) * sBb + (long)(z & 7) * sBh;
  long coff = (long)(z >> 3) * sCb + (long)(z & 7) * sCh;

  __shared__ __attribute__((aligned(16))) bf16 sA[128 * 40];
  __shared__ __attribute__((aligned(16))) bf16 sB[128 * 40];

  int tid  = threadIdx.x;
  int lane = tid & 63;
  int wave = tid >> 6;
  int wm = (wave >> 1) * 64;
  int wn = (wave & 1) * 64;
  int bm0 = blockIdx.y * 128;
  int bn0 = blockIdx.x * 128;

  f32x4 acc[4][4];
  #pragma unroll
  for (int i = 0; i < 4; ++i)
    #pragma unroll
    for (int j = 0; j < 4; ++j)
      #pragma unroll
      for (int r = 0; r < 4; ++r) acc[i][j][r] = 0.f;

  for (int k0 = 0; k0 < K; k0 += 32) {
    #pragma unroll
    for (int i = 0; i < 2; ++i) {
      int linear = (i * 256 + tid) * 8;
      int r = linear >> 5;
      int c = linear & 31;
      bf16x8 va = load_g8(A, (long)(bm0 + r), lda, k0 + c, M, K);
      *(bf16x8*)(&sA[r * 40 + c]) = va;
      bf16x8 vb = load_g8(B, (long)(bn0 + r), ldb, k0 + c, N, K);
      *(bf16x8*)(&sB[r * 40 + c]) = vb;
    }
    __syncthreads();
    bf16x8 aF[4], bF[4];
    #pragma unroll
    for (int i = 0; i < 4; ++i)
      aF[i] = *(const bf16x8*)(&sA[(wm + i * 16 + (lane & 15)) * 40 + (lane >> 4) * 8]);
    #pragma unroll
    for (int j = 0; j < 4; ++j)
      bF[j] = *(const bf16x8*)(&sB[(wn + j * 16 + (lane & 15)) * 40 + (lane >> 4) * 8]);
    #pragma unroll
    for (int i = 0; i < 4; ++i)
      #pragma unroll
      for (int j = 0; j < 4; ++j)
        acc[i][j] = __builtin_amdgcn_mfma_f32_16x16x32_bf16(aF[i], bF[j], acc[i][j], 0, 0, 0);
    __syncthreads();
  }

  int r0 = (lane >> 4) * 4;
  int cc = lane & 15;
  #pragma unroll
  for (int j = 0; j < 4; ++j) {
    int gn = bn0 + wn + j * 16 + cc;
    if (gn >= N) continue;
    float bv = (mode & MODE_BIAS) ? bias[gn] : 0.f;
    #pragma unroll
    for (int i = 0; i < 4; ++i) {
      #pragma unroll
      for (int r = 0; r < 4; ++r) {
        int gm = bm0 + wm + i * 16 + r0 + r;
        if (gm >= M) continue;
        float v = acc[i][j][r];
        if (mode & MODE_MASK) v = v * scale + ((gn > gm) ? -1e9f : 0.f);
        v += bv;
        if (mode & MODE_RES) v += res[(long)gm * ldc + gn];
        if (mode & MODE_RELU) v = fmaxf(v, 0.f);
        if (mode & MODE_F32) Cf[coff + (long)gm * ldc + gn] = v;
        if (mode & MODE_VT) {
          int bl = gm / 168;
          int s  = gm - bl * 168;
          int hh = gn >> 9;
          int dd = gn & 511;
          Cb[((long)(bl * 8 + hh) * 512 + dd) * 168 + s] = (bf16)v;
        } else if (mode & MODE_BF16) {
          Cb[coff + (long)gm * ldc + gn] = (bf16)v;
        }
      }
    }
  }
}

// ---------------------------------------------------------------------------
// Weight transpose + f32->bf16: in [z][K][N] f32 -> out[z*ostride + obase + n*K + k]
// ---------------------------------------------------------------------------
__global__ __launch_bounds__(256) void transpose_w(const float* __restrict__ in,
                                                   bf16* __restrict__ out,
                                                   int K, int N, long ostride, long obase)
{
  long zi = (long)blockIdx.z * K * N;
  long zo = (long)blockIdx.z * ostride + obase;
  __shared__ float t[32][33];
  int tx = threadIdx.x & 31;
  int ty = threadIdx.x >> 5;
  int n0 = blockIdx.x * 32;
  int k0 = blockIdx.y * 32;
  #pragma unroll
  for (int r = 0; r < 4; ++r) {
    int k = k0 + ty + r * 8, n = n0 + tx;
    if (k < K && n < N) t[ty + r * 8][tx] = in[zi + (long)k * N + n];
  }
  __syncthreads();
  #pragma unroll
  for (int r = 0; r < 4; ++r) {
    int n = n0 + ty + r * 8, k = k0 + tx;
    if (n < N && k < K) out[zo + (long)n * K + k] = (bf16)t[tx][ty + r * 8];
  }
}

// merged QKV bias: [L][12288] from three [L][4096]
__global__ __launch_bounds__(256) void merge_bias(const float* __restrict__ q,
                                                  const float* __restrict__ k,
                                                  const float* __restrict__ v,
                                                  float* __restrict__ o)
{
  int idx = blockIdx.x * 256 + threadIdx.x;
  if (idx >= 4 * 12288) return;
  int l = idx / 12288, r = idx - l * 12288;
  int part = r >> 12, n = r & 4095;
  const float* s = (part == 0) ? q : (part == 1) ? k : v;
  o[idx] = s[l * 4096 + n];
}

// ---------------------------------------------------------------------------
// Input projection: h = (x @ in_w + in_b) * sqrt(512) + pos_encoding
// ---------------------------------------------------------------------------
__global__ __launch_bounds__(256) void input_proj(const float* __restrict__ x,
                                                  const float* __restrict__ w,
                                                  const float* __restrict__ b,
                                                  float* __restrict__ hf,
                                                  bf16* __restrict__ hb)
{
  long idx = (long)blockIdx.x * 256 + threadIdx.x;
  long row = idx >> 9;
  int d = (int)(idx & 511);
  float acc = b[d];
  const float* xr = x + row * 10;
  #pragma unroll
  for (int f = 0; f < 10; ++f) acc += xr[f] * w[f * 512 + d];
  int s = (int)(row % 168);
  float rate = __expf(-(float)(d & ~1) * (9.210340371976184f / 512.f));
  float ang = (float)s * rate;
  float pe = (d & 1) ? cosf(ang) : sinf(ang);
  float v = acc * 22.627416997969522f + pe;
  hf[idx] = v;
  hb[idx] = (bf16)v;
}

// ---------------------------------------------------------------------------
// Row softmax (fallback path only)
// ---------------------------------------------------------------------------
__global__ __launch_bounds__(256) void softmax_rows(const float* __restrict__ S,
                                                    bf16* __restrict__ P, int rows)
{
  int row = blockIdx.x * 4 + (threadIdx.x >> 6);
  if (row >= rows) return;
  int lane = threadIdx.x & 63;
  const float* x = S + (long)row * 168;
  float v[3];
  float m = -1e30f;
  #pragma unroll
  for (int t = 0; t < 3; ++t) {
    int c = lane + t * 64;
    v[t] = (c < 168) ? x[c] : -1e30f;
    m = fmaxf(m, v[t]);
  }
  #pragma unroll
  for (int o = 32; o > 0; o >>= 1) m = fmaxf(m, __shfl_xor(m, o, 64));
  float ssum = 0.f;
  #pragma unroll
  for (int t = 0; t < 3; ++t) {
    int c = lane + t * 64;
    v[t] = (c < 168) ? expf(v[t] - m) : 0.f;
    ssum += v[t];
  }
  #pragma unroll
  for (int o = 32; o > 0; o >>= 1) ssum += __shfl_xor(ssum, o, 64);
  float inv = 1.f / ssum;
  #pragma unroll
  for (int t = 0; t < 3; ++t) {
    int c = lane + t * 64;
    if (c < 168) P[(long)row * 168 + c] = (bf16)(v[t] * inv);
  }
}

// ---------------------------------------------------------------------------
// LayerNorm over 512 (fallback path only)
// ---------------------------------------------------------------------------
__device__ __forceinline__ float block_sum256(float v, float* red)
{
  #pragma unroll
  for (int o = 32; o > 0; o >>= 1) v += __shfl_xor(v, o, 64);
  if ((threadIdx.x & 63) == 0) red[threadIdx.x >> 6] = v;
  __syncthreads();
  float tot = red[0] + red[1] + red[2] + red[3];
  __syncthreads();
  return tot;
}

__global__ __launch_bounds__(256) void ln_kernel(const float* __restrict__ X,
                                                 const float* __restrict__ g,
                                                 const float* __restrict__ bta,
                                                 float* __restrict__ Yf,
                                                 bf16* __restrict__ Yb)
{
  __shared__ float red[4];
  long row = blockIdx.x;
  int t = threadIdx.x;
  const float* x = X + row * 512;
  float v0 = x[t], v1 = x[t + 256];
  float mean = block_sum256(v0 + v1, red) * (1.f / 512.f);
  float d0 = v0 - mean, d1 = v1 - mean;
  float var = block_sum256(d0 * d0 + d1 * d1, red) * (1.f / 512.f);
  float rs = rsqrtf(var + 1e-9f);
  float y0 = d0 * rs * g[t] + bta[t];
  float y1 = d1 * rs * g[t + 256] + bta[t + 256];
  Yf[row * 512 + t] = y0;
  Yf[row * 512 + t + 256] = y1;
  Yb[row * 512 + t] = (bf16)y0;
  Yb[row * 512 + t + 256] = (bf16)y1;
}

// ---------------------------------------------------------------------------
// Output projection
// ---------------------------------------------------------------------------
__global__ __launch_bounds__(256) void out_proj(const float* __restrict__ hf,
                                                const float* __restrict__ ow,
                                                const float* __restrict__ ob,
                                                float* __restrict__ out)
{
  int gid = blockIdx.x * 256 + threadIdx.x;
  int wid = gid >> 6;
  int lane = gid & 63;
  if (wid >= 64 * 48) return;
  int b = wid / 48, j = wid - b * 48;
  long row = (long)b * 168 + 120 + j;
  const float* x = hf + row * 512;
  float s = 0.f;
  #pragma unroll
  for (int t = 0; t < 8; ++t) s += x[lane + t * 64] * ow[lane + t * 64];
  #pragma unroll
  for (int o = 32; o > 0; o >>= 1) s += __shfl_xor(s, o, 64);
  if (lane == 0) out[wid] = s + ob[0];
}

// ---------------------------------------------------------------------------
extern "C" void kernel_launch(void* const* d_in, const int* in_sizes, int n_in,
                              void* d_out, int out_size, void* d_ws, size_t ws_size,
                              hipStream_t stream)
{
  const float* x     = (const float*)d_in[0];
  const float* in_w  = (const float*)d_in[2];
  const float* in_b  = (const float*)d_in[3];
  const float* wq_w  = (const float*)d_in[4];
  const float* wq_b  = (const float*)d_in[5];
  const float* wk_w  = (const float*)d_in[6];
  const float* wk_b  = (const float*)d_in[7];
  const float* wv_w  = (const float*)d_in[8];
  const float* wv_b  = (const float*)d_in[9];
  const float* dn_w  = (const float*)d_in[10];
  const float* dn_b  = (const float*)d_in[11];
  const float* mh_w  = (const float*)d_in[12];
  const float* mh_b  = (const float*)d_in[13];
  const float* mo_w  = (const float*)d_in[14];
  const float* mo_b  = (const float*)d_in[15];
  const float* ln1_g = (const float*)d_in[16];
  const float* ln1_b = (const float*)d_in[17];
  const float* ln3_g = (const float*)d_in[18];
  const float* ln3_b = (const float*)d_in[19];
  const float* out_w = (const float*)d_in[20];
  const float* out_b = (const float*)d_in[21];
  float* out = (float*)d_out;

  auto al = [](size_t b) { return (b + 255) & ~(size_t)255; };
  size_t off = 0;
  auto alloc = [&](size_t bytes) -> char* {
    char* p = (char*)d_ws + off;
    off += al(bytes);
    return p;
  };

  // --- fixed buffers ---
  bf16*  wqkvT = (bf16*)alloc(4L * 12288 * 512 * 2);  // [L][12288][512]
  float* qkvB  = (float*)alloc(4L * 12288 * 4);       // [L][12288]
  bf16*  dnT   = (bf16*)alloc(4L * 512 * 4096 * 2);
  bf16*  mhT   = (bf16*)alloc(4L * 2048 * 512 * 2);
  bf16*  moT   = (bf16*)alloc(4L * 512 * 2048 * 2);
  float* hF    = (float*)alloc(10752L * 512 * 4);
  bf16*  hB    = (bf16*)alloc(10752L * 512 * 2);
  size_t fixed = off;

  // --- pick batch-chunk size CB from ws_size ---
  auto chunkBytes = [&](long CB) -> size_t {
    long Mc = CB * 168;
    return al((size_t)Mc * 4096 * 2) * 4              // Qc,Kc,Vtc,Oc
         + al((size_t)Mc * 512 * 4) * 2               // Xc, h1f
         + al((size_t)Mc * 512 * 2)                   // h1b
         + al((size_t)Mc * 2048 * 2);                 // m1c
  };
  int CB = 64;
  while (CB > 1 && fixed + chunkBytes(CB) > ws_size) CB >>= 1;
  int NC = 64 / CB;
  long Mc = (long)CB * 168;
  bool fastOK = (Mc % 128) == 0;  // CB >= 16

  bf16*  Qc  = (bf16*)alloc((size_t)Mc * 4096 * 2);
  bf16*  Kc  = (bf16*)alloc((size_t)Mc * 4096 * 2);
  bf16*  Vtc = (bf16*)alloc((size_t)Mc * 4096 * 2);
  bf16*  Oc  = (bf16*)alloc((size_t)Mc * 4096 * 2);
  float* Xc  = (float*)alloc((size_t)Mc * 512 * 4);
  float* h1f = (float*)alloc((size_t)Mc * 512 * 4);
  bf16*  h1b = (bf16*)alloc((size_t)Mc * 512 * 2);
  bf16*  m1c = (bf16*)alloc((size_t)Mc * 2048 * 2);

  // --- weight prep ---
  transpose_w<<<dim3(128, 16, 4), 256, 0, stream>>>(wq_w, wqkvT, 512, 4096, 12288L * 512, 0);
  transpose_w<<<dim3(128, 16, 4), 256, 0, stream>>>(wk_w, wqkvT, 512, 4096, 12288L * 512, 4096L * 512);
  transpose_w<<<dim3(128, 16, 4), 256, 0, stream>>>(wv_w, wqkvT, 512, 4096, 12288L * 512, 8192L * 512);
  transpose_w<<<dim3(16, 128, 4), 256, 0, stream>>>(dn_w, dnT, 4096, 512, 512L * 4096, 0);
  transpose_w<<<dim3(64, 16, 4), 256, 0, stream>>>(mh_w, mhT, 512, 2048, 2048L * 512, 0);
  transpose_w<<<dim3(16, 64, 4), 256, 0, stream>>>(mo_w, moT, 2048, 512, 512L * 2048, 0);
  merge_bias<<<(4 * 12288 + 255) / 256, 256, 0, stream>>>(wq_b, wk_b, wv_b, qkvB);

  input_proj<<<10752 * 512 / 256, 256, 0, stream>>>(x, in_w, in_b, hF, hB);

  int cM = (int)((Mc + 127) / 128);
  int lnG = (int)(Mc / 64);

  for (int l = 0; l < 4; ++l) {
    for (int c = 0; c < NC; ++c) {
      long row0 = (long)c * Mc;
      const bf16* hBc = hB + row0 * 512;
      const float* hFc = hF + row0 * 512;

      if (fastOK) {
        gemm_fast<<<dim3(96, cM), 256, 0, stream>>>(
            hBc, wqkvT + (long)l * 12288 * 512, nullptr, Qc,
            qkvB + (long)l * 12288, nullptr,
            12288, 512, 512, 512, 0, Mc * 4096, MODE_BIAS | MODE_QKV);

        attn_fused<<<dim3(3, CB * 8), 256, 0, stream>>>(Qc, Kc, Vtc, Oc);

        // dn + residual + ln1 fused
        gemm_ln<<<lnG, 512, 0, stream>>>(
            Oc, dnT + (long)l * 512 * 4096, dn_b + (long)l * 512, hFc,
            ln1_g + l * 512, ln1_b + l * 512, h1f, h1b, 4096);

        gemm_fast<<<dim3(16, cM), 256, 0, stream>>>(
            h1b, mhT + (long)l * 2048 * 512, nullptr, m1c,
            mh_b + (long)l * 2048, nullptr,
            2048, 512, 512, 512, 2048, 0, MODE_BIAS | MODE_RELU | MODE_BF16);

        // mo + residual + ln3 fused
        gemm_ln<<<lnG, 512, 0, stream>>>(
            m1c, moT + (long)l * 512 * 2048, mo_b + (long)l * 512, h1f,
            ln3_g + l * 512, ln3_b + l * 512,
            hF + row0 * 512, hB + row0 * 512, 2048);
      } else {
        gemm_bt<<<dim3(32, cM, 1), 256, 0, stream>>>(
            hBc, wqkvT + (long)l * 12288 * 512, nullptr, Qc, qkvB + (long)l * 12288, nullptr,
            (int)Mc, 4096, 512, 512, 512, 4096, 0, 0, 0, 0, 0, 0, MODE_BIAS | MODE_BF16, 1.f);
        gemm_bt<<<dim3(32, cM, 1), 256, 0, stream>>>(
            hBc, wqkvT + (long)l * 12288 * 512 + 4096L * 512, nullptr, Kc,
            qkvB + (long)l * 12288 + 4096, nullptr,
            (int)Mc, 4096, 512, 512, 512, 4096, 0, 0, 0, 0, 0, 0, MODE_BIAS | MODE_BF16, 1.f);
        gemm_bt<<<dim3(32, cM, 1), 256, 0, stream>>>(
            hBc, wqkvT + (long)l * 12288 * 512 + 8192L * 512, nullptr, Vtc,
            qkvB + (long)l * 12288 + 8192, nullptr,
            (int)Mc, 4096, 512, 512, 512, 4096, 0, 0, 0, 0, 0, 0, MODE_BIAS | MODE_VT, 1.f);

        attn_fused<<<dim3(3, CB * 8), 256, 0, stream>>>(Qc, Kc, Vtc, Oc);

        gemm_bt<<<dim3(4, cM, 1), 256, 0, stream>>>(
            Oc, dnT + (long)l * 512 * 4096, Xc, nullptr, dn_b + (long)l * 512, hFc,
            (int)Mc, 512, 4096, 4096, 4096, 512, 0, 0, 0, 0, 0, 0,
            MODE_BIAS | MODE_RES | MODE_F32, 1.f);
        ln_kernel<<<(int)Mc, 256, 0, stream>>>(Xc, ln1_g + l * 512, ln1_b + l * 512, h1f, h1b);
        gemm_bt<<<dim3(16, cM, 1), 256, 0, stream>>>(
            h1b, mhT + (long)l * 2048 * 512, nullptr, m1c, mh_b + (long)l * 2048, nullptr,
            (int)Mc, 2048, 512, 512, 512, 2048, 0, 0, 0, 0, 0, 0,
            MODE_BIAS | MODE_RELU | MODE_BF16, 1.f);
        gemm_bt<<<dim3(4, cM, 1), 256, 0, stream>>>(
            m1c, moT + (long)l * 512 * 2048, Xc, nullptr, mo_b + (long)l * 512, h1f,
            (int)Mc, 512, 2048, 2048, 2048, 512, 0, 0, 0, 0, 0, 0,
            MODE_BIAS | MODE_RES | MODE_F32, 1.f);
        ln_kernel<<<(int)Mc, 256, 0, stream>>>(Xc, ln3_g + l * 512, ln3_b + l * 512,
                                               hF + row0 * 512, hB + row0 * 512);
      }
    }
  }

  out_proj<<<(64 * 48 * 64) / 256, 256, 0, stream>>>(hF, out_w, out_b, out);
}

// Round 5
// 3989.492 us; speedup vs baseline: 1.4432x; 1.4432x over previous
//
#include <hip/hip_runtime.h>
#include <hip/hip_bf16.h>

typedef __bf16 bf16;
typedef __bf16 bf16x8 __attribute__((ext_vector_type(8)));
typedef float f32x4 __attribute__((ext_vector_type(4)));

#define MODE_BIAS 1
#define MODE_RELU 2
#define MODE_BF16 4
#define MODE_F32  8
#define MODE_RES  16   // f32 residual
#define MODE_RESB 32   // bf16 residual
#define MODE_QKV  128

// ---------------------------------------------------------------------------
// Async 16B global->LDS stage
// ---------------------------------------------------------------------------
__device__ __forceinline__ void stage16(const bf16* g, bf16* l)
{
  __builtin_amdgcn_global_load_lds(
      (const __attribute__((address_space(1))) void*)g,
      (__attribute__((address_space(3))) void*)l, 16, 0, 0);
}

// ---------------------------------------------------------------------------
// gemm2: C[M,N] = A[M,K]*B^T (B is [N,K]).  M%128==0, N%128==0, K%64==0.
// 128x128 tile, BK=64 as two [128][32] k-slabs (8 stage16/wave, 32 MFMA/wave
// between barriers).  grid = (mblocks, nblocks): consecutive blocks share the
// B tile (weight locality).  Epilogue modes: bias, relu, f32/bf16 residual,
// f32/bf16 store, merged-QKV split store with LDS-transposed coalesced V.
// ---------------------------------------------------------------------------
__global__ __launch_bounds__(256) void gemm2(
    const bf16* __restrict__ A, const bf16* __restrict__ B,
    float* __restrict__ Cf, bf16* __restrict__ Cb,
    const float* __restrict__ bias, const float* __restrict__ resf,
    const bf16* __restrict__ resb,
    int N, int K, int lda, int ldb, int ldc, long qstride, int mode)
{
  __shared__ __attribute__((aligned(16))) bf16 smem[16384];  // 32 KB
  bf16* sA = smem;            // [2][128][32]
  bf16* sB = smem + 8192;     // [2][128][32]

  int tid  = threadIdx.x;
  int lane = tid & 63;
  int wave = tid >> 6;
  int wm = (wave >> 1) * 64;
  int wn = (wave & 1) * 64;
  int bm0 = blockIdx.x * 128;
  int bn0 = blockIdx.y * 128;

  f32x4 acc[4][4];
  #pragma unroll
  for (int i = 0; i < 4; ++i)
    #pragma unroll
    for (int j = 0; j < 4; ++j)
      #pragma unroll
      for (int r = 0; r < 4; ++r) acc[i][j][r] = 0.f;

  int seg0 = wave, seg1 = wave + 4;
  int o0 = seg0 * 1024 + lane * 16;
  int r0s = o0 >> 6, c0b = o0 & 63;
  int o1 = seg1 * 1024 + lane * 16;
  int r1s = o1 >> 6, c1b = o1 & 63;

  const char* gA0 = (const char*)A + ((long)(bm0 + r0s) * lda) * 2 + c0b;
  const char* gA1 = (const char*)A + ((long)(bm0 + r1s) * lda) * 2 + c1b;
  const char* gB0 = (const char*)B + ((long)(bn0 + r0s) * ldb) * 2 + c0b;
  const char* gB1 = (const char*)B + ((long)(bn0 + r1s) * ldb) * 2 + c1b;

  for (int k0 = 0; k0 < K; k0 += 64) {
    const char* pA0 = gA0 + (long)k0 * 2;
    const char* pA1 = gA1 + (long)k0 * 2;
    const char* pB0 = gB0 + (long)k0 * 2;
    const char* pB1 = gB1 + (long)k0 * 2;
    stage16((const bf16*)pA0,        sA + seg0 * 512);
    stage16((const bf16*)pA1,        sA + seg1 * 512);
    stage16((const bf16*)(pA0 + 64), sA + 4096 + seg0 * 512);
    stage16((const bf16*)(pA1 + 64), sA + 4096 + seg1 * 512);
    stage16((const bf16*)pB0,        sB + seg0 * 512);
    stage16((const bf16*)pB1,        sB + seg1 * 512);
    stage16((const bf16*)(pB0 + 64), sB + 4096 + seg0 * 512);
    stage16((const bf16*)(pB1 + 64), sB + 4096 + seg1 * 512);
    __syncthreads();
    #pragma unroll
    for (int kh = 0; kh < 2; ++kh) {
      bf16x8 aF[4], bF[4];
      #pragma unroll
      for (int i = 0; i < 4; ++i)
        aF[i] = *(const bf16x8*)(&sA[kh * 4096 + (wm + i * 16 + (lane & 15)) * 32 + (lane >> 4) * 8]);
      #pragma unroll
      for (int j = 0; j < 4; ++j)
        bF[j] = *(const bf16x8*)(&sB[kh * 4096 + (wn + j * 16 + (lane & 15)) * 32 + (lane >> 4) * 8]);
      #pragma unroll
      for (int i = 0; i < 4; ++i)
        #pragma unroll
        for (int j = 0; j < 4; ++j)
          acc[i][j] = __builtin_amdgcn_mfma_f32_16x16x32_bf16(aF[i], bF[j], acc[i][j], 0, 0, 0);
    }
    __syncthreads();
  }

  int lg = lane >> 4;
  int r0 = lg * 4;
  int cc = lane & 15;

  if ((mode & MODE_QKV) && bn0 >= 8192) {
    // ---- V: transposed coalesced store via LDS (smem reused; K-loop done) ----
    bf16* sS = smem;   // [64][130]
    int nn0 = bn0 - 8192;
    #pragma unroll
    for (int ph = 0; ph < 2; ++ph) {
      if ((wn >> 6) == ph) {
        #pragma unroll
        for (int j = 0; j < 4; ++j) {
          int nl = j * 16 + cc;
          float bv = bias[bn0 + wn + j * 16 + cc];
          #pragma unroll
          for (int i = 0; i < 4; ++i)
            #pragma unroll
            for (int r = 0; r < 4; ++r) {
              int m = wm + i * 16 + r0 + r;
              sS[nl * 130 + m] = (bf16)(acc[i][j][r] + bv);
            }
        }
      }
      __syncthreads();
      #pragma unroll
      for (int u = 0; u < 16; ++u) {
        int nrow = u * 4 + wave;
        int d = nn0 + ph * 64 + nrow;
        int hh = d >> 9, dd = d & 511;
        unsigned int pv = *(const unsigned int*)&sS[nrow * 130 + lane * 2];
        int m0 = bm0 + 2 * lane;
        int bl = m0 / 168;
        int s  = m0 - bl * 168;     // even -> pair stays in row
        *(unsigned int*)&Cb[2 * qstride + ((long)(bl * 8 + hh) * 512 + dd) * 168 + s] = pv;
      }
      __syncthreads();
    }
    return;
  }

  #pragma unroll
  for (int j = 0; j < 4; ++j) {
    int gn = bn0 + wn + j * 16 + cc;
    float bv = (mode & MODE_BIAS) ? bias[gn] : 0.f;
    #pragma unroll
    for (int i = 0; i < 4; ++i) {
      #pragma unroll
      for (int r = 0; r < 4; ++r) {
        int gm = bm0 + wm + i * 16 + r0 + r;
        float v = acc[i][j][r] + bv;
        if (mode & MODE_RES)  v += resf[(long)gm * ldc + gn];
        if (mode & MODE_RESB) v += (float)resb[(long)gm * ldc + gn];
        if (mode & MODE_RELU) v = fmaxf(v, 0.f);
        if (mode & MODE_QKV) {
          int part = gn >> 12;          // 0=Q 1=K (V handled above)
          int n = gn & 4095;
          Cb[(long)part * qstride + (long)gm * 4096 + n] = (bf16)v;
        } else if (mode & MODE_F32) {
          Cf[(long)gm * ldc + gn] = v;
        } else {
          Cb[(long)gm * ldc + gn] = (bf16)v;
        }
      }
    }
  }
}

// ---------------------------------------------------------------------------
// FUSED ATTENTION: per (m-tile of 64 q-rows, local bh) block.
// O may alias Q (in-place): each block reads only its own Q rows (fully,
// during phase 1) and writes only its own O rows afterwards.
// ---------------------------------------------------------------------------
__global__ __launch_bounds__(256) void attn_fused(
    const bf16* __restrict__ Q, const bf16* __restrict__ K,
    const bf16* __restrict__ Vt, bf16* __restrict__ O)
{
  __shared__ __attribute__((aligned(16))) bf16 sQ[64 * 32];
  __shared__ __attribute__((aligned(16))) bf16 sK[192 * 32];
  __shared__ __attribute__((aligned(16))) bf16 sP[64 * 200];
  __shared__ __attribute__((aligned(16))) bf16 sV[256 * 32];

  int mt = blockIdx.x;
  int bh = blockIdx.y;
  int bl = bh >> 3, h = bh & 7;
  int tid = threadIdx.x, lane = tid & 63, wave = tid >> 6;

  const bf16* Qb = Q + ((long)bl * 168 + mt * 64) * 4096 + h * 512;
  const bf16* Kb = K + (long)bl * 168 * 4096 + h * 512;
  const bf16* Vb = Vt + (long)bh * 512 * 168;

  #pragma unroll
  for (int idx = tid; idx < 64 * 16; idx += 256) {
    int rr = idx >> 4;
    sP[rr * 200 + 176 + (idx & 15)] = (bf16)0.f;
  }

  int o = wave * 1024 + lane * 16;
  int srw = o >> 6, scb = o & 63;

  const char* gQ = (const char*)Qb + (long)srw * 8192 + scb;
  const char* gK = (const char*)Kb + (long)srw * 8192 + scb;

  f32x4 sacc[11];
  #pragma unroll
  for (int j = 0; j < 11; ++j)
    #pragma unroll
    for (int r = 0; r < 4; ++r) sacc[j][r] = 0.f;

  for (int k0 = 0; k0 < 512; k0 += 32) {
    stage16((const bf16*)(gQ + (long)k0 * 2), &sQ[wave * 512]);
    stage16((const bf16*)(gK + (long)k0 * 2), &sK[wave * 512]);
    stage16((const bf16*)(gK + 64 * 8192 + (long)k0 * 2), &sK[(wave + 4) * 512]);
    stage16((const bf16*)(gK + 128 * 8192 + (long)k0 * 2), &sK[(wave + 8) * 512]);
    __syncthreads();
    bf16x8 aF = *(const bf16x8*)(&sQ[(wave * 16 + (lane & 15)) * 32 + (lane >> 4) * 8]);
    #pragma unroll
    for (int j = 0; j < 11; ++j) {
      bf16x8 bF = *(const bf16x8*)(&sK[(j * 16 + (lane & 15)) * 32 + (lane >> 4) * 8]);
      sacc[j] = __builtin_amdgcn_mfma_f32_16x16x32_bf16(aF, bF, sacc[j], 0, 0, 0);
    }
    __syncthreads();
  }

  int rbase = wave * 16 + ((lane >> 4) << 2);
  #pragma unroll
  for (int r = 0; r < 4; ++r) {
    int srow = mt * 64 + rbase + r;
    float mx = -1e30f;
    #pragma unroll
    for (int j = 0; j < 11; ++j) {
      int col = j * 16 + (lane & 15);
      float v = sacc[j][r] * 0.04419417382415922f;
      v = (col <= srow) ? v : -1e9f;
      sacc[j][r] = v;
      mx = fmaxf(mx, v);
    }
    #pragma unroll
    for (int off = 1; off < 16; off <<= 1) mx = fmaxf(mx, __shfl_xor(mx, off, 16));
    float sum = 0.f;
    #pragma unroll
    for (int j = 0; j < 11; ++j) {
      float e = __expf(sacc[j][r] - mx);
      sacc[j][r] = e;
      sum += e;
    }
    #pragma unroll
    for (int off = 1; off < 16; off <<= 1) sum += __shfl_xor(sum, off, 16);
    float inv = 1.f / sum;
    #pragma unroll
    for (int j = 0; j < 11; ++j)
      sP[(rbase + r) * 200 + j * 16 + (lane & 15)] = (bf16)(sacc[j][r] * inv);
  }

  const char* gV = (const char*)Vb + (long)srw * 336 + scb;
  #pragma unroll 1
  for (int nc = 0; nc < 2; ++nc) {
    f32x4 oacc[16];
    #pragma unroll
    for (int t = 0; t < 16; ++t)
      #pragma unroll
      for (int r = 0; r < 4; ++r) oacc[t][r] = 0.f;

    for (int k0 = 0; k0 < 192; k0 += 32) {
      #pragma unroll
      for (int u = 0; u < 4; ++u)
        stage16((const bf16*)(gV + (long)(nc * 256 + u * 64) * 336 + (long)k0 * 2),
                &sV[(wave + u * 4) * 512]);
      __syncthreads();
      bf16x8 aF = *(const bf16x8*)(&sP[(wave * 16 + (lane & 15)) * 200 + k0 + (lane >> 4) * 8]);
      #pragma unroll
      for (int t = 0; t < 16; ++t) {
        bf16x8 bF = *(const bf16x8*)(&sV[(t * 16 + (lane & 15)) * 32 + (lane >> 4) * 8]);
        oacc[t] = __builtin_amdgcn_mfma_f32_16x16x32_bf16(aF, bF, oacc[t], 0, 0, 0);
      }
      __syncthreads();
    }
    #pragma unroll
    for (int t = 0; t < 16; ++t) {
      int d = nc * 256 + t * 16 + (lane & 15);
      #pragma unroll
      for (int r = 0; r < 4; ++r) {
        int srow = mt * 64 + rbase + r;
        if (srow < 168)
          O[((long)bl * 168 + srow) * 4096 + h * 512 + d] = (bf16)oacc[t][r];
      }
    }
  }
}

// ---------------------------------------------------------------------------
// Weight transpose + f32->bf16
// ---------------------------------------------------------------------------
__global__ __launch_bounds__(256) void transpose_w(const float* __restrict__ in,
                                                   bf16* __restrict__ out,
                                                   int K, int N, long ostride, long obase)
{
  long zi = (long)blockIdx.z * K * N;
  long zo = (long)blockIdx.z * ostride + obase;
  __shared__ float t[32][33];
  int tx = threadIdx.x & 31;
  int ty = threadIdx.x >> 5;
  int n0 = blockIdx.x * 32;
  int k0 = blockIdx.y * 32;
  #pragma unroll
  for (int r = 0; r < 4; ++r) {
    int k = k0 + ty + r * 8, n = n0 + tx;
    if (k < K && n < N) t[ty + r * 8][tx] = in[zi + (long)k * N + n];
  }
  __syncthreads();
  #pragma unroll
  for (int r = 0; r < 4; ++r) {
    int n = n0 + ty + r * 8, k = k0 + tx;
    if (n < N && k < K) out[zo + (long)n * K + k] = (bf16)t[tx][ty + r * 8];
  }
}

__global__ __launch_bounds__(256) void merge_bias(const float* __restrict__ q,
                                                  const float* __restrict__ k,
                                                  const float* __restrict__ v,
                                                  float* __restrict__ o)
{
  int idx = blockIdx.x * 256 + threadIdx.x;
  if (idx >= 4 * 12288) return;
  int l = idx / 12288, r = idx - l * 12288;
  int part = r >> 12, n = r & 4095;
  const float* s = (part == 0) ? q : (part == 1) ? k : v;
  o[idx] = s[l * 4096 + n];
}

// ---------------------------------------------------------------------------
// Input projection: h = (x @ in_w + in_b) * sqrt(512) + pos_encoding
// ---------------------------------------------------------------------------
__global__ __launch_bounds__(256) void input_proj(const float* __restrict__ x,
                                                  const float* __restrict__ w,
                                                  const float* __restrict__ b,
                                                  float* __restrict__ hf,
                                                  bf16* __restrict__ hb)
{
  long idx = (long)blockIdx.x * 256 + threadIdx.x;
  long row = idx >> 9;
  int d = (int)(idx & 511);
  float acc = b[d];
  const float* xr = x + row * 10;
  #pragma unroll
  for (int f = 0; f < 10; ++f) acc += xr[f] * w[f * 512 + d];
  int s = (int)(row % 168);
  float rate = __expf(-(float)(d & ~1) * (9.210340371976184f / 512.f));
  float ang = (float)s * rate;
  float pe = (d & 1) ? cosf(ang) : sinf(ang);
  float v = acc * 22.627416997969522f + pe;
  hf[idx] = v;
  hb[idx] = (bf16)v;
}

// ---------------------------------------------------------------------------
// LayerNorm over 512; Yf write optional (nullptr -> skip)
// ---------------------------------------------------------------------------
__device__ __forceinline__ float block_sum256(float v, float* red)
{
  #pragma unroll
  for (int o = 32; o > 0; o >>= 1) v += __shfl_xor(v, o, 64);
  if ((threadIdx.x & 63) == 0) red[threadIdx.x >> 6] = v;
  __syncthreads();
  float tot = red[0] + red[1] + red[2] + red[3];
  __syncthreads();
  return tot;
}

__global__ __launch_bounds__(256) void ln_kernel(const float* __restrict__ X,
                                                 const float* __restrict__ g,
                                                 const float* __restrict__ bta,
                                                 float* __restrict__ Yf,
                                                 bf16* __restrict__ Yb)
{
  __shared__ float red[4];
  long row = blockIdx.x;
  int t = threadIdx.x;
  const float* x = X + row * 512;
  float v0 = x[t], v1 = x[t + 256];
  float mean = block_sum256(v0 + v1, red) * (1.f / 512.f);
  float d0 = v0 - mean, d1 = v1 - mean;
  float var = block_sum256(d0 * d0 + d1 * d1, red) * (1.f / 512.f);
  float rs = rsqrtf(var + 1e-9f);
  float y0 = d0 * rs * g[t] + bta[t];
  float y1 = d1 * rs * g[t + 256] + bta[t + 256];
  if (Yf) {
    Yf[row * 512 + t] = y0;
    Yf[row * 512 + t + 256] = y1;
  }
  Yb[row * 512 + t] = (bf16)y0;
  Yb[row * 512 + t + 256] = (bf16)y1;
}

// ---------------------------------------------------------------------------
// Output projection
// ---------------------------------------------------------------------------
__global__ __launch_bounds__(256) void out_proj(const float* __restrict__ hf,
                                                const float* __restrict__ ow,
                                                const float* __restrict__ ob,
                                                float* __restrict__ out)
{
  int gid = blockIdx.x * 256 + threadIdx.x;
  int wid = gid >> 6;
  int lane = gid & 63;
  if (wid >= 64 * 48) return;
  int b = wid / 48, j = wid - b * 48;
  long row = (long)b * 168 + 120 + j;
  const float* x = hf + row * 512;
  float s = 0.f;
  #pragma unroll
  for (int t = 0; t < 8; ++t) s += x[lane + t * 64] * ow[lane + t * 64];
  #pragma unroll
  for (int o = 32; o > 0; o >>= 1) s += __shfl_xor(s, o, 64);
  if (lane == 0) out[wid] = s + ob[0];
}

// ---------------------------------------------------------------------------
extern "C" void kernel_launch(void* const* d_in, const int* in_sizes, int n_in,
                              void* d_out, int out_size, void* d_ws, size_t ws_size,
                              hipStream_t stream)
{
  const float* x     = (const float*)d_in[0];
  const float* in_w  = (const float*)d_in[2];
  const float* in_b  = (const float*)d_in[3];
  const float* wq_w  = (const float*)d_in[4];
  const float* wq_b  = (const float*)d_in[5];
  const float* wk_w  = (const float*)d_in[6];
  const float* wk_b  = (const float*)d_in[7];
  const float* wv_w  = (const float*)d_in[8];
  const float* wv_b  = (const float*)d_in[9];
  const float* dn_w  = (const float*)d_in[10];
  const float* dn_b  = (const float*)d_in[11];
  const float* mh_w  = (const float*)d_in[12];
  const float* mh_b  = (const float*)d_in[13];
  const float* mo_w  = (const float*)d_in[14];
  const float* mo_b  = (const float*)d_in[15];
  const float* ln1_g = (const float*)d_in[16];
  const float* ln1_b = (const float*)d_in[17];
  const float* ln3_g = (const float*)d_in[18];
  const float* ln3_b = (const float*)d_in[19];
  const float* out_w = (const float*)d_in[20];
  const float* out_b = (const float*)d_in[21];
  float* out = (float*)d_out;

  auto al = [](size_t b) { return (b + 255) & ~(size_t)255; };
  size_t off = 0;
  auto alloc = [&](size_t bytes) -> char* {
    char* p = (char*)d_ws + off;
    off += al(bytes);
    return p;
  };

  // --- persistent buffers (total ~205 MB; ws known >= ~230 MB from CB=16 runs) ---
  bf16*  wqkvT = (bf16*)alloc(4L * 12288 * 512 * 2);  // [L][12288][512]
  float* qkvB  = (float*)alloc(4L * 12288 * 4);
  bf16*  dnT   = (bf16*)alloc(4L * 512 * 4096 * 2);
  bf16*  mhT   = (bf16*)alloc(4L * 2048 * 512 * 2);
  bf16*  moT   = (bf16*)alloc(4L * 512 * 2048 * 2);
  float* hF    = (float*)alloc(10752L * 512 * 4);     // residual stream f32
  bf16*  hB    = (bf16*)alloc(10752L * 512 * 2);      // residual stream bf16
  float* Xf    = (float*)alloc(10752L * 512 * 4);     // pre-LN full-M scratch

  // chunk region: Qc,Kc,Vtc for CB=16 (Mc=2688); O aliases Qc (in-place);
  // after the chunk loop this region is reused for h1b + m1c.
  const int  CB = 16, NC = 4;
  const long Mc = (long)CB * 168;                     // 2688
  const long qstride = Mc * 4096;                     // elems
  bf16* Qc = (bf16*)alloc((size_t)(3 * qstride) * 2); // 66 MB
  bf16* Kc  = Qc + qstride;
  bf16* Vtc = Qc + 2 * qstride;
  bf16* h1b = Qc;                                     // [10752,512]  (alias)
  bf16* m1c = Qc + 10752L * 512;                      // [10752,2048] (alias)

  // --- weight prep ---
  transpose_w<<<dim3(128, 16, 4), 256, 0, stream>>>(wq_w, wqkvT, 512, 4096, 12288L * 512, 0);
  transpose_w<<<dim3(128, 16, 4), 256, 0, stream>>>(wk_w, wqkvT, 512, 4096, 12288L * 512, 4096L * 512);
  transpose_w<<<dim3(128, 16, 4), 256, 0, stream>>>(wv_w, wqkvT, 512, 4096, 12288L * 512, 8192L * 512);
  transpose_w<<<dim3(16, 128, 4), 256, 0, stream>>>(dn_w, dnT, 4096, 512, 512L * 4096, 0);
  transpose_w<<<dim3(64, 16, 4), 256, 0, stream>>>(mh_w, mhT, 512, 2048, 2048L * 512, 0);
  transpose_w<<<dim3(16, 64, 4), 256, 0, stream>>>(mo_w, moT, 2048, 512, 512L * 2048, 0);
  merge_bias<<<(4 * 12288 + 255) / 256, 256, 0, stream>>>(wq_b, wk_b, wv_b, qkvB);

  input_proj<<<10752 * 512 / 256, 256, 0, stream>>>(x, in_w, in_b, hF, hB);

  const int cM = (int)(Mc / 128);   // 21

  for (int l = 0; l < 4; ++l) {
    // ---- chunked: QKV -> attention (O in-place over Qc) -> dn+res -> Xf ----
    for (int c = 0; c < NC; ++c) {
      long row0 = (long)c * Mc;

      gemm2<<<dim3(cM, 96), 256, 0, stream>>>(
          hB + row0 * 512, wqkvT + (long)l * 12288 * 512, nullptr, Qc,
          qkvB + (long)l * 12288, nullptr, nullptr,
          12288, 512, 512, 512, 0, qstride, MODE_BIAS | MODE_QKV);

      attn_fused<<<dim3(3, CB * 8), 256, 0, stream>>>(Qc, Kc, Vtc, Qc);

      gemm2<<<dim3(cM, 4), 256, 0, stream>>>(
          Qc, dnT + (long)l * 512 * 4096, Xf + row0 * 512, nullptr,
          dn_b + (long)l * 512, hF + row0 * 512, nullptr,
          512, 4096, 4096, 4096, 512, 0, MODE_BIAS | MODE_RES | MODE_F32);
    }

    // ---- full-M: ln1 -> h1b (bf16 only; overwrites dead chunk region) ----
    ln_kernel<<<10752, 256, 0, stream>>>(Xf, ln1_g + l * 512, ln1_b + l * 512,
                                         nullptr, h1b);

    // ---- full-M MLP ----
    gemm2<<<dim3(84, 16), 256, 0, stream>>>(
        h1b, mhT + (long)l * 2048 * 512, nullptr, m1c,
        mh_b + (long)l * 2048, nullptr, nullptr,
        2048, 512, 512, 512, 2048, 0, MODE_BIAS | MODE_RELU | MODE_BF16);

    gemm2<<<dim3(84, 4), 256, 0, stream>>>(
        m1c, moT + (long)l * 512 * 2048, Xf, nullptr,
        mo_b + (long)l * 512, nullptr, h1b,
        512, 2048, 2048, 2048, 512, 0, MODE_BIAS | MODE_RESB | MODE_F32);

    ln_kernel<<<10752, 256, 0, stream>>>(Xf, ln3_g + l * 512, ln3_b + l * 512,
                                         hF, hB);
  }

  out_proj<<<(64 * 48 * 64) / 256, 256, 0, stream>>>(hF, out_w, out_b, out);
}